// Round 1
// baseline (7669.353 us; speedup 1.0000x reference)
//
#include <hip/hip_runtime.h>
#include <hip/hip_bf16.h>

typedef _Float16 f16;
typedef _Float16 f16x8 __attribute__((ext_vector_type(8)));
typedef float f32x4 __attribute__((ext_vector_type(4)));

#define B_ 128
#define T_ 256
#define D_ 1280
#define G3_ 3840
#define C_ 100
#define TB_ 32768  /* T_*B_ */

// ---- workspace layout (bytes) ----
#define O_SEQB 0ull                 // f16 [TB_][D_]   (row = t*128+b)
#define O_WIH  83886080ull          // f16 [G3_][D_]
#define O_WHH  93716480ull          // f16 [G3_][D_]
#define O_XP   103546880ull         // f16 [TB_][G3_]  (row = t*128+b)
#define O_H16  355205120ull         // f16 [2][B_][D_]
#define O_H32  355860480ull         // f32 [B_][D_]
#define O_BAR  356515840ull         // unsigned counter

// ---------------- conversion / init ----------------
__global__ void k_convert(const float* __restrict__ seq, const float* __restrict__ wih,
                          const float* __restrict__ whh, f16* __restrict__ seqb,
                          f16* __restrict__ wih16, f16* __restrict__ whh16,
                          unsigned* __restrict__ bar) {
  if (blockIdx.x == 0 && threadIdx.x == 0) *bar = 0u;
  const long NSEQ = (long)TB_ * (D_ / 8);
  const long NW = (long)G3_ * (D_ / 8);
  const long total = NSEQ + 2 * NW;
  for (long i = (long)blockIdx.x * blockDim.x + threadIdx.x; i < total;
       i += (long)gridDim.x * blockDim.x) {
    const float* src;
    f16* dst;
    if (i < NSEQ) {
      long row = i / (D_ / 8), c = i % (D_ / 8);
      long t = row >> 7, b = row & 127;
      src = seq + ((b * T_ + t) * (long)D_ + c * 8);
      dst = seqb + (row * (long)D_ + c * 8);
    } else if (i < NSEQ + NW) {
      long j = i - NSEQ;
      src = wih + j * 8;
      dst = wih16 + j * 8;
    } else {
      long j = i - NSEQ - NW;
      src = whh + j * 8;
      dst = whh16 + j * 8;
    }
    float4 a = *(const float4*)src, b4 = *(const float4*)(src + 4);
    f16x8 o;
    o[0] = (f16)a.x; o[1] = (f16)a.y; o[2] = (f16)a.z; o[3] = (f16)a.w;
    o[4] = (f16)b4.x; o[5] = (f16)b4.y; o[6] = (f16)b4.z; o[7] = (f16)b4.w;
    *(f16x8*)dst = o;
  }
}

// ---------------- x_proj GEMM: [32768,1280] @ [3840,1280]^T -> f16 [32768,3840] ----------------
__device__ __forceinline__ void gl_lds16(const f16* g, f16* lds) {
  __builtin_amdgcn_global_load_lds((const __attribute__((address_space(1))) void*)g,
                                   (__attribute__((address_space(3))) void*)lds, 16, 0, 0);
}

__global__ __launch_bounds__(256) void k_xproj(const f16* __restrict__ A, const f16* __restrict__ Bw,
                                               const float* __restrict__ bih, f16* __restrict__ Cout) {
  __shared__ f16 Alds[128 * 32];
  __shared__ f16 Blds[128 * 32];
  int bid = blockIdx.x;
  // superblock swizzle: 8 bm-tiles x 30 bn-tiles per superblock (keeps W_ih hot)
  int sb = bid / 240;
  int wi = bid % 240;
  int bm = sb * 8 + (wi & 7);
  int bn = wi >> 3;
  long brow = (long)bm * 128;
  int bcol = bn * 128;
  int tid = threadIdx.x, w = tid >> 6, l = tid & 63;
  int wm = w & 1, wn = w >> 1;

  f32x4 acc[4][4] = {};

  int sr = w * 32 + (l >> 2);   // staging row (first instr), +16 for second
  int sc = (l & 3) * 8;         // k-elem offset (16B chunk)
  const f16* gA = A + (brow + sr) * (long)D_ + sc;
  const f16* gB = Bw + (long)(bcol + sr) * D_ + sc;
  f16* lAw = Alds + (w * 32) * 32;  // wave-uniform LDS dest base
  f16* lBw = Blds + (w * 32) * 32;

  int fr = l & 15, fc = (l >> 4) * 8;

  for (int kb = 0; kb < 40; ++kb) {
    const f16* a0 = gA + kb * 32;
    const f16* b0 = gB + kb * 32;
    gl_lds16(a0, lAw);
    gl_lds16(a0 + 16 * D_, lAw + 16 * 32);
    gl_lds16(b0, lBw);
    gl_lds16(b0 + 16 * D_, lBw + 16 * 32);
    __syncthreads();
    f16x8 af[4], bf[4];
#pragma unroll
    for (int mt = 0; mt < 4; ++mt) af[mt] = *(const f16x8*)(Alds + (wm * 64 + mt * 16 + fr) * 32 + fc);
#pragma unroll
    for (int nt = 0; nt < 4; ++nt) bf[nt] = *(const f16x8*)(Blds + (wn * 64 + nt * 16 + fr) * 32 + fc);
#pragma unroll
    for (int mt = 0; mt < 4; ++mt)
#pragma unroll
      for (int nt = 0; nt < 4; ++nt)
        acc[mt][nt] = __builtin_amdgcn_mfma_f32_16x16x32_f16(af[mt], bf[nt], acc[mt][nt], 0, 0, 0);
    __syncthreads();
  }
  // epilogue: add b_ih, store f16
#pragma unroll
  for (int nt = 0; nt < 4; ++nt) {
    int col = bcol + wn * 64 + nt * 16 + fr;
    float bv = bih[col];
#pragma unroll
    for (int mt = 0; mt < 4; ++mt) {
#pragma unroll
      for (int i = 0; i < 4; ++i) {
        long row = brow + wm * 64 + mt * 16 + (l >> 4) * 4 + i;
        Cout[row * G3_ + col] = (f16)(acc[mt][nt][i] + bv);
      }
    }
  }
}

// ---------------- grid barrier (monotone counter) ----------------
__device__ __forceinline__ void grid_barrier(unsigned* bar, unsigned target) {
  __syncthreads();
  if (threadIdx.x == 0) {
    __threadfence();
    __hip_atomic_fetch_add(bar, 1u, __ATOMIC_ACQ_REL, __HIP_MEMORY_SCOPE_AGENT);
    while (__hip_atomic_load(bar, __ATOMIC_ACQUIRE, __HIP_MEMORY_SCOPE_AGENT) < target)
      __builtin_amdgcn_s_sleep(2);
  }
  __syncthreads();
  __threadfence();
}

// ---------------- GRU scan: persistent, 160 blocks (2 rowgrp x 80 colgrp) ----------------
__global__ __launch_bounds__(256, 1) void k_scan(const f16* __restrict__ whh16,
                                                 const f16* __restrict__ xproj,
                                                 const float* __restrict__ bhh,
                                                 f16* __restrict__ h16, float* __restrict__ h32,
                                                 unsigned* __restrict__ bar) {
  __shared__ f16 wlds[3 * 16 * D_];  // 120 KB, XOR-swizzled 16B chunks
  int wg = blockIdx.x;
  int rg = wg / 80, cg = wg % 80;
  int r0 = rg * 64, d0 = cg * 16;
  int tid = threadIdx.x, w = tid >> 6, l = tid & 63;
  int wr0 = r0 + w * 16;
  int fr = l & 15, fq = l >> 4;
  int mycol = d0 + fr;

  // load W_hh chunk into LDS (once, lives for all 256 steps)
  for (int q = tid; q < 3 * 16 * (D_ / 8); q += 256) {
    int gj = q / 160, c = q % 160;
    int j = gj & 15, g = gj >> 4;
    uint4 v = *(const uint4*)(whh16 + ((long)(g * D_ + d0 + j)) * D_ + c * 8);
    *(uint4*)(wlds + (gj * 160 + (c ^ (j & 7))) * 8) = v;
  }
  // zero h16[0] own tile (exact cover across the grid)
#pragma unroll
  for (int i = 0; i < 4; ++i) h16[(wr0 + fq * 4 + i) * D_ + mycol] = (f16)0.f;

  float bh0 = bhh[0 * D_ + mycol];
  float bh1 = bhh[1 * D_ + mycol];
  float bh2 = bhh[2 * D_ + mycol];
  float hreg[4] = {0.f, 0.f, 0.f, 0.f};

  unsigned tgt = 160;
  grid_barrier(bar, tgt);
  tgt += 160;

  int cur = 0;
  for (int t = 0; t < T_; ++t) {
    const f16* hc = h16 + cur * (B_ * D_);
    const f16* arow = hc + (wr0 + fr) * (long)D_ + fq * 8;
    f32x4 acc0 = {}, acc1 = {}, acc2 = {};
#pragma unroll 8
    for (int kb = 0; kb < 40; ++kb) {
      f16x8 a = *(const f16x8*)(arow + kb * 32);
      int cs = (kb * 4 + fq) ^ (fr & 7);
      f16x8 b0 = *(const f16x8*)(wlds + ((0 * 16 + fr) * 160 + cs) * 8);
      f16x8 b1 = *(const f16x8*)(wlds + ((1 * 16 + fr) * 160 + cs) * 8);
      f16x8 b2 = *(const f16x8*)(wlds + ((2 * 16 + fr) * 160 + cs) * 8);
      acc0 = __builtin_amdgcn_mfma_f32_16x16x32_f16(a, b0, acc0, 0, 0, 0);
      acc1 = __builtin_amdgcn_mfma_f32_16x16x32_f16(a, b1, acc1, 0, 0, 0);
      acc2 = __builtin_amdgcn_mfma_f32_16x16x32_f16(a, b2, acc2, 0, 0, 0);
    }
    const f16* xp = xproj + ((long)t * B_) * G3_;
    f16* hn = h16 + (cur ^ 1) * (B_ * D_);
#pragma unroll
    for (int i = 0; i < 4; ++i) {
      int row = wr0 + fq * 4 + i;
      const f16* xr = xp + (long)row * G3_ + mycol;
      float gr = (float)xr[0], gz = (float)xr[D_], gn = (float)xr[2 * D_];
      float r = 1.f / (1.f + __expf(-(gr + acc0[i] + bh0)));
      float z = 1.f / (1.f + __expf(-(gz + acc1[i] + bh1)));
      float pn = gn + r * (acc2[i] + bh2);
      pn = fminf(fmaxf(pn, -30.f), 30.f);
      float e = __expf(-2.f * pn);
      float n = (1.f - e) / (1.f + e);
      float hv = (1.f - z) * n + z * hreg[i];
      hreg[i] = hv;
      hn[row * D_ + mycol] = (f16)hv;
      if (t == T_ - 1) h32[row * D_ + mycol] = hv;
    }
    grid_barrier(bar, tgt);
    tgt += 160;
    cur ^= 1;
  }
}

// ---------------- scores: out[b][c] = sum_d h[b][d]*cand[b][c][d] (fp32) ----------------
__global__ __launch_bounds__(256) void k_scores(const float* __restrict__ h32,
                                                const float* __restrict__ cand,
                                                float* __restrict__ out) {
  int gw = blockIdx.x * 4 + (threadIdx.x >> 6);
  int l = threadIdx.x & 63;
  int b = gw / C_, c = gw % C_;
  const float* hp = h32 + (long)b * D_;
  const float* cp = cand + ((long)b * C_ + c) * D_;
  float s = 0.f;
#pragma unroll
  for (int q = 0; q < 5; ++q) {
    int d = q * 256 + l * 4;
    float4 hv = *(const float4*)(hp + d);
    float4 cv = *(const float4*)(cp + d);
    s += hv.x * cv.x + hv.y * cv.y + hv.z * cv.z + hv.w * cv.w;
  }
#pragma unroll
  for (int off = 32; off > 0; off >>= 1) s += __shfl_down(s, off);
  if (l == 0) out[(long)b * C_ + c] = s;
}

extern "C" void kernel_launch(void* const* d_in, const int* in_sizes, int n_in, void* d_out,
                              int out_size, void* d_ws, size_t ws_size, hipStream_t stream) {
  const float* seq = (const float*)d_in[0];
  const float* cand = (const float*)d_in[1];
  const float* wih = (const float*)d_in[2];
  const float* whh = (const float*)d_in[3];
  const float* bih = (const float*)d_in[4];
  const float* bhh = (const float*)d_in[5];
  char* ws = (char*)d_ws;
  f16* seqb = (f16*)(ws + O_SEQB);
  f16* wih16 = (f16*)(ws + O_WIH);
  f16* whh16 = (f16*)(ws + O_WHH);
  f16* xp = (f16*)(ws + O_XP);
  f16* h16 = (f16*)(ws + O_H16);
  float* h32 = (float*)(ws + O_H32);
  unsigned* bar = (unsigned*)(ws + O_BAR);

  k_convert<<<2048, 256, 0, stream>>>(seq, wih, whh, seqb, wih16, whh16, bar);
  k_xproj<<<7680, 256, 0, stream>>>(seqb, wih16, bih, xp);
  k_scan<<<160, 256, 0, stream>>>(whh16, xp, bhh, h16, h32, bar);
  k_scores<<<3200, 256, 0, stream>>>(h32, cand, (float*)d_out);
}

// Round 2
// 4024.568 us; speedup vs baseline: 1.9056x; 1.9056x over previous
//
#include <hip/hip_runtime.h>
#include <hip/hip_bf16.h>

typedef _Float16 f16;
typedef _Float16 f16x8 __attribute__((ext_vector_type(8)));
typedef float f32x4 __attribute__((ext_vector_type(4)));

#define B_ 128
#define T_ 256
#define D_ 1280
#define G3_ 3840
#define C_ 100
#define TB_ 32768  /* T_*B_ */

// ---- workspace layout (bytes) ----
#define O_SEQB 0ull                 // f16 [TB_][D_]   (row = t*128+b)
#define O_WIH  83886080ull          // f16 [G3_][D_]
#define O_WHH  93716480ull          // f16 [G3_][D_]
#define O_XP   103546880ull         // f16 [TB_][G3_]  (row = t*128+b)
#define O_H16  355205120ull         // f16 [2][B_][D_]
#define O_H32  355860480ull         // f32 [B_][D_]
#define O_BAR  356515840ull         // unsigned counters (2 rowgroups, 64B apart)

// ---------------- conversion / init ----------------
__global__ void k_convert(const float* __restrict__ seq, const float* __restrict__ wih,
                          const float* __restrict__ whh, f16* __restrict__ seqb,
                          f16* __restrict__ wih16, f16* __restrict__ whh16,
                          unsigned* __restrict__ bar) {
  if (blockIdx.x == 0 && threadIdx.x < 32) bar[threadIdx.x] = 0u;
  const long NSEQ = (long)TB_ * (D_ / 8);
  const long NW = (long)G3_ * (D_ / 8);
  const long total = NSEQ + 2 * NW;
  for (long i = (long)blockIdx.x * blockDim.x + threadIdx.x; i < total;
       i += (long)gridDim.x * blockDim.x) {
    const float* src;
    f16* dst;
    if (i < NSEQ) {
      long row = i / (D_ / 8), c = i % (D_ / 8);
      long t = row >> 7, b = row & 127;
      src = seq + ((b * T_ + t) * (long)D_ + c * 8);
      dst = seqb + (row * (long)D_ + c * 8);
    } else if (i < NSEQ + NW) {
      long j = i - NSEQ;
      src = wih + j * 8;
      dst = wih16 + j * 8;
    } else {
      long j = i - NSEQ - NW;
      src = whh + j * 8;
      dst = whh16 + j * 8;
    }
    float4 a = *(const float4*)src, b4 = *(const float4*)(src + 4);
    f16x8 o;
    o[0] = (f16)a.x; o[1] = (f16)a.y; o[2] = (f16)a.z; o[3] = (f16)a.w;
    o[4] = (f16)b4.x; o[5] = (f16)b4.y; o[6] = (f16)b4.z; o[7] = (f16)b4.w;
    *(f16x8*)dst = o;
  }
}

// ---------------- x_proj GEMM: [32768,1280] @ [3840,1280]^T -> f16 [32768,3840] ----------------
__device__ __forceinline__ void gl_lds16(const f16* g, f16* lds) {
  __builtin_amdgcn_global_load_lds((const __attribute__((address_space(1))) void*)g,
                                   (__attribute__((address_space(3))) void*)lds, 16, 0, 0);
}

__global__ __launch_bounds__(256) void k_xproj(const f16* __restrict__ A, const f16* __restrict__ Bw,
                                               const float* __restrict__ bih, f16* __restrict__ Cout) {
  __shared__ f16 Alds[128 * 32];
  __shared__ f16 Blds[128 * 32];
  int bid = blockIdx.x;
  // superblock swizzle: 8 bm-tiles x 30 bn-tiles per superblock (keeps W_ih hot)
  int sb = bid / 240;
  int wi = bid % 240;
  int bm = sb * 8 + (wi & 7);
  int bn = wi >> 3;
  long brow = (long)bm * 128;
  int bcol = bn * 128;
  int tid = threadIdx.x, w = tid >> 6, l = tid & 63;
  int wm = w & 1, wn = w >> 1;

  f32x4 acc[4][4] = {};

  int sr = w * 32 + (l >> 2);   // staging row (first instr), +16 for second
  int sc = (l & 3) * 8;         // k-elem offset (16B chunk)
  const f16* gA = A + (brow + sr) * (long)D_ + sc;
  const f16* gB = Bw + (long)(bcol + sr) * D_ + sc;
  f16* lAw = Alds + (w * 32) * 32;  // wave-uniform LDS dest base
  f16* lBw = Blds + (w * 32) * 32;

  int fr = l & 15, fc = (l >> 4) * 8;

  for (int kb = 0; kb < 40; ++kb) {
    const f16* a0 = gA + kb * 32;
    const f16* b0 = gB + kb * 32;
    gl_lds16(a0, lAw);
    gl_lds16(a0 + 16 * D_, lAw + 16 * 32);
    gl_lds16(b0, lBw);
    gl_lds16(b0 + 16 * D_, lBw + 16 * 32);
    __syncthreads();
    f16x8 af[4], bf[4];
#pragma unroll
    for (int mt = 0; mt < 4; ++mt) af[mt] = *(const f16x8*)(Alds + (wm * 64 + mt * 16 + fr) * 32 + fc);
#pragma unroll
    for (int nt = 0; nt < 4; ++nt) bf[nt] = *(const f16x8*)(Blds + (wn * 64 + nt * 16 + fr) * 32 + fc);
#pragma unroll
    for (int mt = 0; mt < 4; ++mt)
#pragma unroll
      for (int nt = 0; nt < 4; ++nt)
        acc[mt][nt] = __builtin_amdgcn_mfma_f32_16x16x32_f16(af[mt], bf[nt], acc[mt][nt], 0, 0, 0);
    __syncthreads();
  }
  // epilogue: add b_ih, store f16
#pragma unroll
  for (int nt = 0; nt < 4; ++nt) {
    int col = bcol + wn * 64 + nt * 16 + fr;
    float bv = bih[col];
#pragma unroll
    for (int mt = 0; mt < 4; ++mt) {
#pragma unroll
      for (int i = 0; i < 4; ++i) {
        long row = brow + wm * 64 + mt * 16 + (l >> 4) * 4 + i;
        Cout[row * G3_ + col] = (f16)(acc[mt][nt][i] + bv);
      }
    }
  }
}

// ---------------- row-group barrier: relaxed add + relaxed poll (no cache ops) ----------------
__device__ __forceinline__ void rg_barrier(unsigned* cnt, unsigned target) {
  __syncthreads();  // drains vmcnt: all h stores (write-through atomics) are LLC-visible
  if (threadIdx.x == 0) {
    __hip_atomic_fetch_add(cnt, 1u, __ATOMIC_RELAXED, __HIP_MEMORY_SCOPE_AGENT);
    unsigned it = 0;
    while (__hip_atomic_load(cnt, __ATOMIC_RELAXED, __HIP_MEMORY_SCOPE_AGENT) < target) {
      __builtin_amdgcn_s_sleep(2);
      if (++it > 1000000u) {  // paranoia fallback: RMW always reads coherent point
        if (__hip_atomic_fetch_add(cnt, 0u, __ATOMIC_RELAXED, __HIP_MEMORY_SCOPE_AGENT) >= target)
          break;
      }
    }
  }
  asm volatile("" ::: "memory");
  __syncthreads();
}

// ---------------- GRU scan: persistent, 160 blocks (2 rowgrp x 80 colgrp) ----------------
__global__ __launch_bounds__(256, 1) void k_scan(const f16* __restrict__ whh16,
                                                 const f16* __restrict__ xproj,
                                                 const float* __restrict__ bhh,
                                                 f16* __restrict__ h16, float* __restrict__ h32,
                                                 unsigned* __restrict__ bar) {
  __shared__ f16 wlds[3 * 16 * D_];  // 120 KB, XOR-swizzled 16B chunks
  int wg = blockIdx.x;
  int rg = wg / 80, cg = wg % 80;
  int r0 = rg * 64, d0 = cg * 16;
  int tid = threadIdx.x, w = tid >> 6, l = tid & 63;
  int wr0 = r0 + w * 16;
  int fr = l & 15, fq = l >> 4;
  int mycol = d0 + fr;
  unsigned* cnt = bar + rg * 16;  // per-rowgroup counter, own cacheline

  // load W_hh chunk into LDS (once, lives for all 256 steps)
  for (int q = tid; q < 3 * 16 * (D_ / 8); q += 256) {
    int gj = q / 160, c = q % 160;
    int j = gj & 15, g = gj >> 4;
    uint4 v = *(const uint4*)(whh16 + ((long)(g * D_ + d0 + j)) * D_ + c * 8);
    *(uint4*)(wlds + (gj * 160 + (c ^ (j & 7))) * 8) = v;
  }
  // zero h16[0] own tile via write-through atomic u32 (pairs of cols, even-fr lanes)
#pragma unroll
  for (int i = 0; i < 4; ++i) {
    if ((fr & 1) == 0) {
      unsigned* p = (unsigned*)(h16 + (wr0 + fq * 4 + i) * D_ + mycol);
      __hip_atomic_store(p, 0u, __ATOMIC_RELAXED, __HIP_MEMORY_SCOPE_AGENT);
    }
  }

  float bh0 = bhh[0 * D_ + mycol];
  float bh1 = bhh[1 * D_ + mycol];
  float bh2 = bhh[2 * D_ + mycol];
  float hreg[4] = {0.f, 0.f, 0.f, 0.f};

  rg_barrier(cnt, 80u);

  int cur = 0;
  for (int t = 0; t < T_; ++t) {
    // prefetch this step's xproj gate values into registers (hidden under K-loop)
    f16 xg0[4], xg1[4], xg2[4];
    {
      const f16* xr0 = xproj + ((long)t * B_ + wr0 + fq * 4) * G3_ + mycol;
#pragma unroll
      for (int i = 0; i < 4; ++i) {
        const f16* xr = xr0 + (long)i * G3_;
        xg0[i] = xr[0]; xg1[i] = xr[D_]; xg2[i] = xr[2 * D_];
      }
    }
    const f16* hc = h16 + cur * (B_ * D_);
    const f16* arow = hc + (wr0 + fr) * (long)D_ + fq * 8;
    f32x4 acc0 = {}, acc1 = {}, acc2 = {};
#pragma unroll 8
    for (int kb = 0; kb < 40; ++kb) {
      union { unsigned long long u[2]; f16x8 v; } a;
      const unsigned long long* ap = (const unsigned long long*)(arow + kb * 32);
      a.u[0] = __hip_atomic_load(ap, __ATOMIC_RELAXED, __HIP_MEMORY_SCOPE_AGENT);
      a.u[1] = __hip_atomic_load(ap + 1, __ATOMIC_RELAXED, __HIP_MEMORY_SCOPE_AGENT);
      int cs = (kb * 4 + fq) ^ (fr & 7);
      f16x8 b0 = *(const f16x8*)(wlds + ((0 * 16 + fr) * 160 + cs) * 8);
      f16x8 b1 = *(const f16x8*)(wlds + ((1 * 16 + fr) * 160 + cs) * 8);
      f16x8 b2 = *(const f16x8*)(wlds + ((2 * 16 + fr) * 160 + cs) * 8);
      acc0 = __builtin_amdgcn_mfma_f32_16x16x32_f16(a.v, b0, acc0, 0, 0, 0);
      acc1 = __builtin_amdgcn_mfma_f32_16x16x32_f16(a.v, b1, acc1, 0, 0, 0);
      acc2 = __builtin_amdgcn_mfma_f32_16x16x32_f16(a.v, b2, acc2, 0, 0, 0);
    }
    f16* hn = h16 + (cur ^ 1) * (B_ * D_);
#pragma unroll
    for (int i = 0; i < 4; ++i) {
      int row = wr0 + fq * 4 + i;
      float gr = (float)xg0[i], gz = (float)xg1[i], gn = (float)xg2[i];
      float r = 1.f / (1.f + __expf(-(gr + acc0[i] + bh0)));
      float z = 1.f / (1.f + __expf(-(gz + acc1[i] + bh1)));
      float pn = gn + r * (acc2[i] + bh2);
      pn = fminf(fmaxf(pn, -30.f), 30.f);
      float e = __expf(-2.f * pn);
      float n = (1.f - e) / (1.f + e);
      float hv = (1.f - z) * n + z * hreg[i];
      hreg[i] = hv;
      // pack col pair across lanes (fr, fr^1) -> one u32 write-through atomic store
      unsigned short bits = __builtin_bit_cast(unsigned short, (f16)hv);
      unsigned other = (unsigned)__shfl_xor((int)bits, 1);
      if ((fr & 1) == 0) {
        unsigned val = (unsigned)bits | (other << 16);
        unsigned* p = (unsigned*)(hn + row * D_ + mycol);
        __hip_atomic_store(p, val, __ATOMIC_RELAXED, __HIP_MEMORY_SCOPE_AGENT);
      }
    }
    rg_barrier(cnt, (unsigned)(t + 2) * 80u);
    cur ^= 1;
  }
  // final h in fp32 for the scores kernel (plain stores; kernel-end flush)
#pragma unroll
  for (int i = 0; i < 4; ++i) {
    int row = wr0 + fq * 4 + i;
    h32[row * D_ + mycol] = hreg[i];
  }
}

// ---------------- scores: out[b][c] = sum_d h[b][d]*cand[b][c][d] (fp32) ----------------
__global__ __launch_bounds__(256) void k_scores(const float* __restrict__ h32,
                                                const float* __restrict__ cand,
                                                float* __restrict__ out) {
  int gw = blockIdx.x * 4 + (threadIdx.x >> 6);
  int l = threadIdx.x & 63;
  int b = gw / C_, c = gw % C_;
  const float* hp = h32 + (long)b * D_;
  const float* cp = cand + ((long)b * C_ + c) * D_;
  float s = 0.f;
#pragma unroll
  for (int q = 0; q < 5; ++q) {
    int d = q * 256 + l * 4;
    float4 hv = *(const float4*)(hp + d);
    float4 cv = *(const float4*)(cp + d);
    s += hv.x * cv.x + hv.y * cv.y + hv.z * cv.z + hv.w * cv.w;
  }
#pragma unroll
  for (int off = 32; off > 0; off >>= 1) s += __shfl_down(s, off);
  if (l == 0) out[(long)b * C_ + c] = s;
}

extern "C" void kernel_launch(void* const* d_in, const int* in_sizes, int n_in, void* d_out,
                              int out_size, void* d_ws, size_t ws_size, hipStream_t stream) {
  const float* seq = (const float*)d_in[0];
  const float* cand = (const float*)d_in[1];
  const float* wih = (const float*)d_in[2];
  const float* whh = (const float*)d_in[3];
  const float* bih = (const float*)d_in[4];
  const float* bhh = (const float*)d_in[5];
  char* ws = (char*)d_ws;
  f16* seqb = (f16*)(ws + O_SEQB);
  f16* wih16 = (f16*)(ws + O_WIH);
  f16* whh16 = (f16*)(ws + O_WHH);
  f16* xp = (f16*)(ws + O_XP);
  f16* h16 = (f16*)(ws + O_H16);
  float* h32 = (float*)(ws + O_H32);
  unsigned* bar = (unsigned*)(ws + O_BAR);

  k_convert<<<2048, 256, 0, stream>>>(seq, wih, whh, seqb, wih16, whh16, bar);
  k_xproj<<<7680, 256, 0, stream>>>(seqb, wih16, bih, xp);
  k_scan<<<160, 256, 0, stream>>>(whh16, xp, bhh, h16, h32, bar);
  k_scores<<<3200, 256, 0, stream>>>(h32, cand, (float*)d_out);
}